// Round 1
// baseline (158.202 us; speedup 1.0000x reference)
//
#include <hip/hip_runtime.h>

// B=65536, C=2, P=41, L=4: loss = mean( ce*w + 0.001*conn )
//   ce   = relu(l_other - l_target) + log(1+exp(-|l1-l0|))
//   w    = 1 + |t[p]-t[p-1]| + |t[p+1]-t[p]| + 0.5(|t[p]-t[p-2]| + |t[p+2]-t[p]|), bounds-guarded
//   conn = (pred[p] != pred[p-1]), p>=1; pred = (l1 > l0)
//
// Round 8: dedup loads via LDS neighbor-sharing. Neighbor (b,p+k) has linear
// index t+k (same b, guard via p-clamp), so a block covering t in
// [blk*256, blk*256+256) holds every neighbor except a 2-wide halo.
// Loads drop 9 -> 3 per thread (144 B -> 48 B issued): targets and the
// logit-diff d are staged in LDS; prev-pred comes from the stored d sign.
constexpr int B    = 65536;
constexpr int P    = 41;
constexpr int NTH  = B * P;          // 2,686,976 = 10,496 * 256 exactly (no tail)
constexpr int BLK  = 256;
constexpr int NBLK = NTH / BLK;      // 10,496
constexpr float INV_N = 1.0f / (float)(B * P * 4);
constexpr float CW    = 0.001f;

__device__ __forceinline__ float comp1(float d, float dm, int tx,
                                       int am1, int ap1, int am2, int ap2)
{
    float g  = __logf(1.0f + __expf(-fabsf(d)));
    float ft = (float)tx;
    float sd = d * fmaf(-2.0f, ft, 1.0f);        // l_other - l_target
    float ce = fmaxf(sd, 0.0f) + g;

    int   x1 = (tx ^ am1) + (tx ^ ap1);          // 0..2
    int   x2 = (tx ^ am2) + (tx ^ ap2);          // 0..2
    float w  = fmaf(0.5f, (float)x2, 1.0f + (float)x1);

    float conn = ((d > 0.0f) != (dm > 0.0f)) ? CW : 0.0f;
    return fmaf(ce, w, conn);
}

__global__ __launch_bounds__(256)
void lace_partial_kernel(const float4* __restrict__ lg4,
                         const int4*   __restrict__ tg4,
                         float*        __restrict__ partial)
{
    // local index: targets at stg[tid+2] (halo 2 each side), d at sdv[tid+1] (halo 1 left)
    __shared__ int4   stg[BLK + 4];
    __shared__ float4 sdv[BLK + 1];

    const int tid = threadIdx.x;
    const int t   = blockIdx.x * BLK + tid;      // (b,p) pair id, no tail
    const int b   = t / P;                        // magic-mul
    const int p   = t - b * P;
    const int f4  = b * 82 + p;                   // float4 idx of logits[b,0,p,:]

    // ---- 3 unconditional loads per thread (unique bytes only) ----
    float4 a0 = lg4[f4];
    float4 a1 = lg4[f4 + 41];
    int4   tc = tg4[t];

    // ---- halos (few lanes; clamped indices are only read when the p-clamp
    //      allows, which also guarantees they were in-range) ----
    if (tid < 2)        stg[tid]     = tg4[max(t - 2, 0)];        // tg4[blkstart-2+tid]
    if (tid >= BLK - 2) stg[tid + 4] = tg4[min(t + 2, NTH - 1)];  // tg4[blkstart+256+(tid-254)]
    if (tid == 0) {
        const int tm = max(t - 1, 0);
        const int bm = tm / P;
        const int pm = tm - bm * P;
        const int fm = bm * 82 + pm;
        float4 q0 = lg4[fm];
        float4 q1 = lg4[fm + 41];
        float4 dh;
        dh.x = q1.x - q0.x; dh.y = q1.y - q0.y;
        dh.z = q1.z - q0.z; dh.w = q1.w - q0.w;
        sdv[0] = dh;
    }

    float4 d4;
    d4.x = a1.x - a0.x; d4.y = a1.y - a0.y;
    d4.z = a1.z - a0.z; d4.w = a1.w - a0.w;

    stg[tid + 2] = tc;
    sdv[tid + 1] = d4;
    __syncthreads();

    // clamp-to-self neighbor OFFSETS (reproduce bounds guards exactly:
    // self XOR self = 0; self-d makes conn=0 at p=0)
    const int om1 = (p >= 1)     ? 1 : 0;
    const int op1 = (p <= P - 2) ? 1 : 0;
    const int om2 = (p >= 2)     ? 2 : 0;        // NOTE: p=1 -> self, not 0
    const int op2 = (p <= P - 3) ? 2 : 0;

    const int li = tid + 2;
    const int4   nA = stg[li - om1];
    const int4   nB = stg[li + op1];
    const int4   nC = stg[li - om2];
    const int4   nD = stg[li + op2];
    const float4 dm = sdv[tid + 1 - om1];

    float sum = comp1(d4.x, dm.x, tc.x, nA.x, nB.x, nC.x, nD.x)
              + comp1(d4.y, dm.y, tc.y, nA.y, nB.y, nC.y, nD.y)
              + comp1(d4.z, dm.z, tc.z, nA.z, nB.z, nC.z, nD.z)
              + comp1(d4.w, dm.w, tc.w, nA.w, nB.w, nC.w, nD.w);

    // ---- block reduction -> one partial per block ----
    #pragma unroll
    for (int off = 32; off > 0; off >>= 1)
        sum += __shfl_down(sum, off, 64);

    __shared__ float wsum[4];
    const int lane = threadIdx.x & 63;
    const int wid  = threadIdx.x >> 6;
    if (lane == 0) wsum[wid] = sum;
    __syncthreads();
    if (threadIdx.x == 0)
        partial[blockIdx.x] = wsum[0] + wsum[1] + wsum[2] + wsum[3];
}

__global__ __launch_bounds__(1024)
void lace_reduce_kernel(const float4* __restrict__ partial4,
                        float*        __restrict__ out)
{
    constexpr int N4 = NBLK / 4;                 // 2624, exact
    float s = 0.0f;
    for (int i = threadIdx.x; i < N4; i += 1024) {
        float4 v = partial4[i];
        s += (v.x + v.y) + (v.z + v.w);
    }

    #pragma unroll
    for (int off = 32; off > 0; off >>= 1)
        s += __shfl_down(s, off, 64);

    __shared__ float wsum[16];
    const int lane = threadIdx.x & 63;
    const int wid  = threadIdx.x >> 6;
    if (lane == 0) wsum[wid] = s;
    __syncthreads();
    if (threadIdx.x == 0) {
        float total = 0.0f;
        #pragma unroll
        for (int i = 0; i < 16; ++i) total += wsum[i];
        out[0] = total * INV_N;
    }
}

extern "C" void kernel_launch(void* const* d_in, const int* in_sizes, int n_in,
                              void* d_out, int out_size, void* d_ws, size_t ws_size,
                              hipStream_t stream) {
    const float4* lg4 = (const float4*)d_in[0];
    const int4*   tg4 = (const int4*)d_in[1];
    float* out     = (float*)d_out;
    float* partial = (float*)d_ws;   // 10,496 floats

    lace_partial_kernel<<<NBLK, 256, 0, stream>>>(lg4, tg4, partial);
    lace_reduce_kernel<<<1, 1024, 0, stream>>>((const float4*)partial, out);
}